// Round 1
// baseline (923.620 us; speedup 1.0000x reference)
//
#include <hip/hip_runtime.h>
#include <cstdint>
#include <cstddef>

typedef __bf16 bf16_t;
typedef __bf16 bf16x8 __attribute__((ext_vector_type(8)));
typedef __bf16 bf16x4 __attribute__((ext_vector_type(4)));
typedef __bf16 bf16x2 __attribute__((ext_vector_type(2)));
typedef float f32x4 __attribute__((ext_vector_type(4)));

#define A_TOTAL 262144
#define NMAP    131072

// ---------------- weight f32 -> bf16 conversion (6 slices of [256][256]) ---
// by: 0=map_W1a 1=map_W1b 2=map_W2 3=sch_W1a 4=sch_W1b 5=sch_W2
__global__ __launch_bounds__(256) void k_w16(
    const float* __restrict__ mW1, const float* __restrict__ mW2,
    const float* __restrict__ sW1, const float* __restrict__ sW2,
    bf16_t* __restrict__ dst) {
  int e = blockIdx.x * 256 + threadIdx.x;     // 0..65535
  int n = e >> 8, k = e & 255;
  float v;
  switch (blockIdx.y) {
    case 0:  v = mW1[n * 512 + k]; break;
    case 1:  v = mW1[n * 512 + 256 + k]; break;
    case 2:  v = mW2[e]; break;
    case 3:  v = sW1[n * 512 + k]; break;
    case 4:  v = sW1[n * 512 + 256 + k]; break;
    default: v = sW2[e]; break;
  }
  dst[(size_t)blockIdx.y * 65536 + e] = (bf16_t)v;
}

// ---------------- column partial sums of all_embeddings [131072][256] ------
__global__ __launch_bounds__(256) void k_mean(const float* __restrict__ A,
                                              float* __restrict__ part) {
  int t = threadIdx.x, b = blockIdx.x;        // 256 blocks x 512 rows
  const float* base = A + (size_t)b * 512 * 256 + t;
  float s = 0.f;
  for (int r = 0; r < 512; ++r) s += base[(size_t)r * 256];
  part[b * 256 + t] = s;
}

// ---------------- g -> query MLP -> q -> qk_pad (bf16 [16][256]) -----------
__global__ __launch_bounds__(256) void k_front(
    const float* __restrict__ meanPart,
    const float* __restrict__ qgW1, const float* __restrict__ qgb1,
    const float* __restrict__ qgW2, const float* __restrict__ qgb2,
    const float* __restrict__ Wq,  const float* __restrict__ bq,
    const float* __restrict__ Wk,  bf16_t* __restrict__ qk_pad) {
  __shared__ float g[256], h1[256], qry[256], qv[256];
  int t = threadIdx.x;
  float s = 0.f;
  for (int b = 0; b < 256; ++b) s += meanPart[b * 256 + t];
  g[t] = s * (1.0f / 131072.0f);
  __syncthreads();
  {
    const f32x4* row = (const f32x4*)(qgW1 + (size_t)t * 256);
    float acc = 0.f;
    for (int k = 0; k < 64; ++k) {
      f32x4 w = row[k];
      acc += w[0] * g[4 * k] + w[1] * g[4 * k + 1] + w[2] * g[4 * k + 2] + w[3] * g[4 * k + 3];
    }
    h1[t] = fmaxf(acc + qgb1[t], 0.f);
  }
  __syncthreads();
  {
    const f32x4* row = (const f32x4*)(qgW2 + (size_t)t * 256);
    float acc = 0.f;
    for (int k = 0; k < 64; ++k) {
      f32x4 w = row[k];
      acc += w[0] * h1[4 * k] + w[1] * h1[4 * k + 1] + w[2] * h1[4 * k + 2] + w[3] * h1[4 * k + 3];
    }
    qry[t] = acc + qgb2[t];
  }
  __syncthreads();
  {
    const f32x4* row = (const f32x4*)(Wq + (size_t)t * 256);
    float acc = 0.f;
    for (int k = 0; k < 64; ++k) {
      f32x4 w = row[k];
      acc += w[0] * qry[4 * k] + w[1] * qry[4 * k + 1] + w[2] * qry[4 * k + 2] + w[3] * qry[4 * k + 3];
    }
    qv[t] = acc + bq[t];
  }
  __syncthreads();
  // qk[h][n] = (1/8) sum_d qv[h*64+d] * Wk[h*64+d][n]   (coalesced over t=n)
  for (int h = 0; h < 4; ++h) {
    float acc = 0.f;
    for (int d = 0; d < 64; ++d) acc += qv[h * 64 + d] * Wk[(size_t)(h * 64 + d) * 256 + t];
    qk_pad[h * 256 + t] = (bf16_t)(acc * 0.125f);
  }
  for (int h = 4; h < 16; ++h) qk_pad[h * 256 + t] = (bf16_t)0.f;
}

// ---------------- GEMM (direct): C[M][256] = bf16( A_f32 @ W^T + bias ) ----
// block 256 thr = 4 waves (2x2), tile 128x128, K=256, MFMA 16x16x32 bf16.
// No LDS: A fragments loaded f32->bf16 directly; W (bf16 [n][k]) from L2.
__global__ __launch_bounds__(256) void gemm_direct(
    const float* __restrict__ A, int M,
    const bf16_t* __restrict__ W, const float* __restrict__ bias,
    bf16_t* __restrict__ C) {
  int t = threadIdx.x;
  int w = t >> 6, lane = t & 63;
  int lm = lane & 15, q = lane >> 4;
  int m0 = blockIdx.y * 128 + (w & 1) * 64;
  int c0 = blockIdx.x * 128 + (w >> 1) * 64;
  int rows[4];
#pragma unroll
  for (int i = 0; i < 4; ++i) {
    int m = m0 + i * 16 + lm;
    rows[i] = m < M ? m : M - 1;
  }
  f32x4 acc[4][4] = {};
#pragma unroll
  for (int kt = 0; kt < 8; ++kt) {
    int k0 = kt * 32 + q * 8;
    bf16x8 b[4];
#pragma unroll
    for (int j = 0; j < 4; ++j)
      b[j] = *(const bf16x8*)(W + (size_t)(c0 + j * 16 + lm) * 256 + k0);
#pragma unroll
    for (int i = 0; i < 4; ++i) {
      const float* src = A + (size_t)rows[i] * 256 + k0;
      f32x4 lo = *(const f32x4*)src;
      f32x4 hi = *(const f32x4*)(src + 4);
      bf16x8 a;
#pragma unroll
      for (int x = 0; x < 4; ++x) { a[x] = (bf16_t)lo[x]; a[x + 4] = (bf16_t)hi[x]; }
#pragma unroll
      for (int j = 0; j < 4; ++j)
        acc[i][j] = __builtin_amdgcn_mfma_f32_16x16x32_bf16(a, b[j], acc[i][j], 0, 0, 0);
    }
  }
#pragma unroll
  for (int j = 0; j < 4; ++j) {
    int col = c0 + j * 16 + lm;
    float bb = bias ? bias[col] : 0.f;
#pragma unroll
    for (int i = 0; i < 4; ++i)
#pragma unroll
      for (int r = 0; r < 4; ++r) {
        int m = m0 + i * 16 + q * 4 + r;
        if (m < M) C[(size_t)m * 256 + col] = (bf16_t)(acc[i][j][r] + bb);
      }
  }
}

// ---------------- GEMM (gather): keys = relu(Pa[ia]+Pb[ib]) @ W2^T + b2 ----
__global__ __launch_bounds__(256) void gemm_gather(
    const bf16_t* __restrict__ Pa, const bf16_t* __restrict__ Pb,
    const int* __restrict__ idxA, const int* __restrict__ idxB,
    const bf16_t* __restrict__ W, const float* __restrict__ bias,
    bf16_t* __restrict__ C) {
  int t = threadIdx.x;
  int w = t >> 6, lane = t & 63;
  int lm = lane & 15, q = lane >> 4;
  int m0 = blockIdx.y * 128 + (w & 1) * 64;
  int c0 = blockIdx.x * 128 + (w >> 1) * 64;
  int ia[4], ib[4];
#pragma unroll
  for (int i = 0; i < 4; ++i) {
    int m = m0 + i * 16 + lm;
    ia[i] = idxA[m];
    ib[i] = idxB[m];
  }
  f32x4 acc[4][4] = {};
#pragma unroll
  for (int kt = 0; kt < 8; ++kt) {
    int k0 = kt * 32 + q * 8;
    bf16x8 b[4];
#pragma unroll
    for (int j = 0; j < 4; ++j)
      b[j] = *(const bf16x8*)(W + (size_t)(c0 + j * 16 + lm) * 256 + k0);
#pragma unroll
    for (int i = 0; i < 4; ++i) {
      bf16x8 pa = *(const bf16x8*)(Pa + (size_t)ia[i] * 256 + k0);
      bf16x8 pb = *(const bf16x8*)(Pb + (size_t)ib[i] * 256 + k0);
      bf16x8 a;
#pragma unroll
      for (int x = 0; x < 8; ++x) {
        float v = (float)pa[x] + (float)pb[x];
        a[x] = (bf16_t)fmaxf(v, 0.f);
      }
#pragma unroll
      for (int j = 0; j < 4; ++j)
        acc[i][j] = __builtin_amdgcn_mfma_f32_16x16x32_bf16(a, b[j], acc[i][j], 0, 0, 0);
    }
  }
#pragma unroll
  for (int j = 0; j < 4; ++j) {
    int col = c0 + j * 16 + lm;
    float bb = bias[col];
#pragma unroll
    for (int i = 0; i < 4; ++i)
#pragma unroll
      for (int r = 0; r < 4; ++r) {
        int m = m0 + i * 16 + q * 4 + r;
        C[(size_t)m * 256 + col] = (bf16_t)(acc[i][j][r] + bb);
      }
  }
}

// ---------------- scores[h][a] = keys[a] . qk[h]  (MFMA, N padded to 16) ---
__global__ __launch_bounds__(256) void k_scores(
    const bf16_t* __restrict__ keys, const bf16_t* __restrict__ qk_pad,
    float* __restrict__ scores, float* __restrict__ partMax) {
  int t = threadIdx.x;
  int w = t >> 6, lane = t & 63;
  int lm = lane & 15, q = lane >> 4;
  int m0 = blockIdx.x * 256 + w * 64;
  bf16x8 b[8];
#pragma unroll
  for (int kt = 0; kt < 8; ++kt)
    b[kt] = *(const bf16x8*)(qk_pad + lm * 256 + kt * 32 + q * 8);
  f32x4 acc[4] = {};
#pragma unroll
  for (int i = 0; i < 4; ++i) {
    const bf16_t* arow = keys + (size_t)(m0 + i * 16 + lm) * 256 + q * 8;
#pragma unroll
    for (int kt = 0; kt < 8; ++kt) {
      bf16x8 a = *(const bf16x8*)(arow + kt * 32);
      acc[i] = __builtin_amdgcn_mfma_f32_16x16x32_bf16(a, b[kt], acc[i], 0, 0, 0);
    }
  }
  float lmax = -3.4e38f;
#pragma unroll
  for (int i = 0; i < 4; ++i)
#pragma unroll
    for (int r = 0; r < 4; ++r) {
      float v = acc[i][r];
      if (lm < 4) {
        scores[(size_t)lm * A_TOTAL + m0 + i * 16 + q * 4 + r] = v;
        lmax = fmaxf(lmax, v);
      }
    }
  // per-head max: reduce over q (lanes lm==h hold head h)
  float v1 = fmaxf(lmax, __shfl_xor(lmax, 16));
  float v2 = fmaxf(v1, __shfl_xor(v1, 32));
  __shared__ float pm[4][4];
  if (lane < 4) pm[w][lane] = v2;
  __syncthreads();
  if (t < 4) {
    float m = fmaxf(fmaxf(pm[0][t], pm[1][t]), fmaxf(pm[2][t], pm[3][t]));
    partMax[t * 1024 + blockIdx.x] = m;
  }
}

// ---------------- scores softmax reductions --------------------------------
__global__ __launch_bounds__(256) void k_smax2(const float* __restrict__ pM,
                                               float* __restrict__ Mh) {
  int t = threadIdx.x;
  __shared__ float red[256];
  for (int h = 0; h < 4; ++h) {
    float m = fmaxf(fmaxf(pM[h * 1024 + t], pM[h * 1024 + 256 + t]),
                    fmaxf(pM[h * 1024 + 512 + t], pM[h * 1024 + 768 + t]));
    red[t] = m;
    __syncthreads();
    for (int s = 128; s > 0; s >>= 1) {
      if (t < s) red[t] = fmaxf(red[t], red[t + s]);
      __syncthreads();
    }
    if (t == 0) Mh[h] = red[0];
    __syncthreads();
  }
}

__global__ __launch_bounds__(256) void k_ssum(const float* __restrict__ scores,
                                              const float* __restrict__ Mh,
                                              float* __restrict__ part) {
  int b = blockIdx.x, t = threadIdx.x;    // 256 blocks, head = b>>6
  float m = Mh[b >> 6];
  const float* base = scores + (size_t)b * 4096;
  float s = 0.f;
  for (int i = 0; i < 16; ++i) s += __expf(base[i * 256 + t] - m);
  __shared__ float red[256];
  red[t] = s;
  __syncthreads();
  for (int st = 128; st > 0; st >>= 1) {
    if (t < st) red[t] += red[t + st];
    __syncthreads();
  }
  if (t == 0) part[b] = red[0];
}

__global__ __launch_bounds__(256) void k_ssum2(const float* __restrict__ part,
                                               float* __restrict__ invS) {
  int t = threadIdx.x;
  __shared__ float red[256];
  red[t] = part[t];
  __syncthreads();
  for (int s = 32; s > 0; s >>= 1) {
    if ((t & 63) < s) red[t] += red[t + s];
    __syncthreads();
  }
  if ((t & 63) == 0) invS[t >> 6] = 1.0f / red[t];
}

// ---------------- u[h] = sum_a w[h,a] * keys[a] ----------------------------
__global__ __launch_bounds__(256) void k_u(
    const bf16_t* __restrict__ keys, const float* __restrict__ scores,
    const float* __restrict__ Mh, const float* __restrict__ invS,
    float* __restrict__ u) {
  __shared__ float wl[4][512];
  __shared__ float uloc[2][4][256];
  int t = threadIdx.x;
  int a0 = blockIdx.x * 512;            // 512 blocks x 512 rows
#pragma unroll
  for (int i = 0; i < 8; ++i) {
    int e = i * 256 + t;                // 0..2047
    int h = e >> 9, r = e & 511;
    wl[h][r] = __expf(scores[(size_t)h * A_TOTAL + a0 + r] - Mh[h]) * invS[h];
  }
  __syncthreads();
  int tc = t & 127, rh = t >> 7;
  float acc[4][2] = {};
  for (int r = 0; r < 256; ++r) {
    int a = a0 + rh * 256 + r;
    bf16x2 kv = *(const bf16x2*)(keys + (size_t)a * 256 + tc * 2);
    float f0 = (float)kv[0], f1 = (float)kv[1];
#pragma unroll
    for (int h = 0; h < 4; ++h) {
      float wv = wl[h][rh * 256 + r];
      acc[h][0] += wv * f0;
      acc[h][1] += wv * f1;
    }
  }
#pragma unroll
  for (int h = 0; h < 4; ++h) {
    uloc[rh][h][tc * 2]     = acc[h][0];
    uloc[rh][h][tc * 2 + 1] = acc[h][1];
  }
  __syncthreads();
#pragma unroll
  for (int h = 0; h < 4; ++h)
    atomicAdd(&u[h * 256 + t], uloc[0][h][t] + uloc[1][h][t]);
}

// ---------------- ctx = u @ Wv_h^T + bv ; attn_out = ctx @ Wo^T + bo -------
__global__ __launch_bounds__(256) void k_attn(
    const float* __restrict__ u, const float* __restrict__ Wv,
    const float* __restrict__ bv, const float* __restrict__ Wo,
    const float* __restrict__ bo, float* __restrict__ attn_out) {
  __shared__ float ctx[256];
  int t = threadIdx.x;
  int h = t >> 6;
  const float* uh = u + h * 256;
  {
    const f32x4* row = (const f32x4*)(Wv + (size_t)t * 256);
    float acc = 0.f;
    for (int k = 0; k < 64; ++k) {
      f32x4 w = row[k];
      acc += w[0] * uh[4 * k] + w[1] * uh[4 * k + 1] + w[2] * uh[4 * k + 2] + w[3] * uh[4 * k + 3];
    }
    ctx[t] = acc + bv[t];
  }
  __syncthreads();
  {
    const f32x4* row = (const f32x4*)(Wo + (size_t)t * 256);
    float acc = 0.f;
    for (int k = 0; k < 64; ++k) {
      f32x4 w = row[k];
      acc += w[0] * ctx[4 * k] + w[1] * ctx[4 * k + 1] + w[2] * ctx[4 * k + 2] + w[3] * ctx[4 * k + 3];
    }
    attn_out[t] = acc + bo[t];
  }
}

// ---------------- logits[a] = keys[a] . attn_out  (+ block max) ------------
__global__ __launch_bounds__(256) void k_logits(
    const bf16_t* __restrict__ keys, const float* __restrict__ attn_out,
    float* __restrict__ out_logits, float* __restrict__ blockMax) {
  int t = threadIdx.x;
  int w = t >> 6, l = t & 63;
  f32x4 ao = *(const f32x4*)(attn_out + l * 4);
  int base = blockIdx.x * 128 + w * 32;
  float lmax = -3.4e38f;
  for (int r = 0; r < 32; ++r) {
    int a = base + r;
    bf16x4 kv = *(const bf16x4*)(keys + (size_t)a * 256 + l * 4);
    float v = (float)kv[0] * ao[0] + (float)kv[1] * ao[1] +
              (float)kv[2] * ao[2] + (float)kv[3] * ao[3];
    for (int off = 32; off > 0; off >>= 1) v += __shfl_xor(v, off);
    if (l == 0) out_logits[a] = v;
    lmax = fmaxf(lmax, v);
  }
  __shared__ float red[4];
  if (l == 0) red[w] = lmax;
  __syncthreads();
  if (t == 0)
    blockMax[blockIdx.x] = fmaxf(fmaxf(red[0], red[1]), fmaxf(red[2], red[3]));
}

__global__ __launch_bounds__(256) void k_lred1(const float* __restrict__ bm,
                                               float* __restrict__ Ml) {
  int t = threadIdx.x;
  float m = -3.4e38f;
  for (int i = t; i < 2048; i += 256) m = fmaxf(m, bm[i]);
  __shared__ float red[256];
  red[t] = m;
  __syncthreads();
  for (int s = 128; s > 0; s >>= 1) {
    if (t < s) red[t] = fmaxf(red[t], red[t + s]);
    __syncthreads();
  }
  if (t == 0) Ml[0] = red[0];
}

__global__ __launch_bounds__(256) void k_lsum(const float* __restrict__ logits,
                                              const float* __restrict__ Ml,
                                              float* __restrict__ part) {
  int t = threadIdx.x, b = blockIdx.x;   // 512 blocks x 512 elems
  float m = Ml[0];
  float s = __expf(logits[b * 512 + t] - m) + __expf(logits[b * 512 + 256 + t] - m);
  __shared__ float red[256];
  red[t] = s;
  __syncthreads();
  for (int st = 128; st > 0; st >>= 1) {
    if (t < st) red[t] += red[t + st];
    __syncthreads();
  }
  if (t == 0) part[b] = red[0];
}

__global__ __launch_bounds__(256) void k_lred2(const float* __restrict__ part,
                                               float* __restrict__ invSl) {
  int t = threadIdx.x;
  float s = part[t] + part[t + 256];
  __shared__ float red[256];
  red[t] = s;
  __syncthreads();
  for (int st = 128; st > 0; st >>= 1) {
    if (t < st) red[t] += red[t + st];
    __syncthreads();
  }
  if (t == 0) invSl[0] = 1.0f / red[0];
}

__global__ __launch_bounds__(256) void k_probs(const float* __restrict__ logits,
                                               const float* __restrict__ Ml,
                                               const float* __restrict__ invSl,
                                               float* __restrict__ probs) {
  int i = blockIdx.x * 256 + threadIdx.x;
  probs[i] = __expf(logits[i] - Ml[0]) * invSl[0];
}

// ===========================================================================
extern "C" void kernel_launch(void* const* d_in, const int* in_sizes, int n_in,
                              void* d_out, int out_size, void* d_ws, size_t ws_size,
                              hipStream_t stream) {
  const float* qubit_emb = (const float*)d_in[0];
  const float* qpu_emb   = (const float*)d_in[1];
  const float* gate_emb  = (const float*)d_in[2];
  const float* all_emb   = (const float*)d_in[3];
  const float* time_tab  = (const float*)d_in[4];
  const float* map_W1 = (const float*)d_in[5];
  const float* map_b1 = (const float*)d_in[6];
  const float* map_W2 = (const float*)d_in[7];
  const float* map_b2 = (const float*)d_in[8];
  const float* sch_W1 = (const float*)d_in[9];
  const float* sch_b1 = (const float*)d_in[10];
  const float* sch_W2 = (const float*)d_in[11];
  const float* sch_b2 = (const float*)d_in[12];
  const float* qg_W1 = (const float*)d_in[13];
  const float* qg_b1 = (const float*)d_in[14];
  const float* qg_W2 = (const float*)d_in[15];
  const float* qg_b2 = (const float*)d_in[16];
  const float* Wq = (const float*)d_in[17];
  const float* bq = (const float*)d_in[18];
  const float* Wk = (const float*)d_in[19];
  // d_in[20] = attn_bk: per-head constant shift, softmax-invariant -> unused
  const float* Wv = (const float*)d_in[21];
  const float* bv = (const float*)d_in[22];
  const float* Wo = (const float*)d_in[23];
  const float* bo = (const float*)d_in[24];
  const int* map_qubit  = (const int*)d_in[25];
  const int* map_qpu    = (const int*)d_in[26];
  const int* sched_gate = (const int*)d_in[27];
  const int* sched_time = (const int*)d_in[28];
  (void)in_sizes; (void)n_in; (void)out_size;

  char* ws = (char*)d_ws;
  size_t off = 0;
  auto alloc = [&](size_t b) { size_t r = off; off += (b + 255) & ~(size_t)255; return r; };
  size_t KEYS  = alloc((size_t)A_TOTAL * 256 * 2);   // bf16 keys
  size_t PQ    = alloc((size_t)65536 * 256 * 2);     // bf16 qubit proj
  size_t PG    = alloc((size_t)65536 * 256 * 2);     // bf16 gate proj
  size_t PP    = alloc((size_t)64 * 256 * 2);        // bf16 qpu proj (+b1)
  size_t PT    = alloc((size_t)1024 * 256 * 2);      // bf16 time proj (+b1), padded
  size_t WB    = alloc((size_t)6 * 65536 * 2);       // bf16 weights
  size_t SCORE = alloc((size_t)4 * A_TOTAL * 4);     // f32 scores [4][A]
  size_t MPART = alloc((size_t)256 * 256 * 4);       // mean partials
  size_t QKPAD = alloc((size_t)16 * 256 * 2);        // bf16 qk padded
  size_t ATTN  = alloc(256 * 4);
  size_t U     = alloc(4 * 256 * 4);
  size_t PMAX  = alloc(4 * 1024 * 4);
  size_t MH    = alloc(4 * 4);
  size_t SINV  = alloc(4 * 4);
  size_t BMAX  = alloc(2048 * 4);
  size_t ML    = alloc(4);
  size_t SLINV = alloc(4);
  size_t LPART = alloc(512 * 4);
  size_t SPART = alloc(256 * 4);
  if (off > ws_size) return;  // insufficient scratch -> loud validation fail

  bf16_t* keysP  = (bf16_t*)(ws + KEYS);
  bf16_t* pqP    = (bf16_t*)(ws + PQ);
  bf16_t* pgP    = (bf16_t*)(ws + PG);
  bf16_t* ppP    = (bf16_t*)(ws + PP);
  bf16_t* ptP    = (bf16_t*)(ws + PT);
  bf16_t* wbP    = (bf16_t*)(ws + WB);
  float*  scoreP = (float*)(ws + SCORE);
  float*  mpartP = (float*)(ws + MPART);
  bf16_t* qkP    = (bf16_t*)(ws + QKPAD);
  float*  attnP  = (float*)(ws + ATTN);
  float*  uP     = (float*)(ws + U);
  float*  pmaxP  = (float*)(ws + PMAX);
  float*  mhP    = (float*)(ws + MH);
  float*  sinvP  = (float*)(ws + SINV);
  float*  bmaxP  = (float*)(ws + BMAX);
  float*  mlP    = (float*)(ws + ML);
  float*  slinvP = (float*)(ws + SLINV);
  float*  lpartP = (float*)(ws + LPART);
  float*  spartP = (float*)(ws + SPART);

  float* probsOut  = (float*)d_out;
  float* logitsOut = probsOut + A_TOTAL;

  hipMemsetAsync(uP, 0, 4 * 256 * 4, stream);

  k_w16<<<dim3(256, 6), 256, 0, stream>>>(map_W1, map_W2, sch_W1, sch_W2, wbP);
  k_mean<<<256, 256, 0, stream>>>(all_emb, mpartP);
  k_front<<<1, 256, 0, stream>>>(mpartP, qg_W1, qg_b1, qg_W2, qg_b2, Wq, bq, Wk, qkP);

  // table projections (layer-1 halves)
  gemm_direct<<<dim3(2, 512), 256, 0, stream>>>(qubit_emb, 65536, wbP + 0 * 65536, nullptr, pqP);
  gemm_direct<<<dim3(2, 512), 256, 0, stream>>>(gate_emb, 65536, wbP + 3 * 65536, nullptr, pgP);
  gemm_direct<<<dim3(2, 1),   256, 0, stream>>>(qpu_emb, 64,    wbP + 1 * 65536, map_b1,  ppP);
  gemm_direct<<<dim3(2, 8),   256, 0, stream>>>(time_tab, 1000, wbP + 4 * 65536, sch_b1,  ptP);

  // keys (gather + relu + layer-2)
  gemm_gather<<<dim3(2, 1024), 256, 0, stream>>>(pqP, ppP, map_qubit, map_qpu,
                                                 wbP + 2 * 65536, map_b2, keysP);
  gemm_gather<<<dim3(2, 1024), 256, 0, stream>>>(pgP, ptP, sched_gate, sched_time,
                                                 wbP + 5 * 65536, sch_b2,
                                                 keysP + (size_t)NMAP * 256);

  // attention scores + softmax stats
  k_scores<<<1024, 256, 0, stream>>>(keysP, qkP, scoreP, pmaxP);
  k_smax2<<<1, 256, 0, stream>>>(pmaxP, mhP);
  k_ssum<<<256, 256, 0, stream>>>(scoreP, mhP, spartP);
  k_ssum2<<<1, 256, 0, stream>>>(spartP, sinvP);

  // weighted key sum -> ctx -> attn_out
  k_u<<<512, 256, 0, stream>>>(keysP, scoreP, mhP, sinvP, uP);
  k_attn<<<1, 256, 0, stream>>>(uP, Wv, bv, Wo, bo, attnP);

  // logits + global softmax
  k_logits<<<2048, 256, 0, stream>>>(keysP, attnP, logitsOut, bmaxP);
  k_lred1<<<1, 256, 0, stream>>>(bmaxP, mlP);
  k_lsum<<<512, 256, 0, stream>>>(logitsOut, mlP, lpartP);
  k_lred2<<<1, 256, 0, stream>>>(lpartP, slinvP);
  k_probs<<<1024, 256, 0, stream>>>(logitsOut, mlP, slinvP, probsOut);
}

// Round 2
// 873.611 us; speedup vs baseline: 1.0572x; 1.0572x over previous
//
#include <hip/hip_runtime.h>
#include <cstdint>
#include <cstddef>

typedef __bf16 bf16_t;
typedef __bf16 bf16x8 __attribute__((ext_vector_type(8)));
typedef __bf16 bf16x4 __attribute__((ext_vector_type(4)));
typedef __bf16 bf16x2 __attribute__((ext_vector_type(2)));
typedef float f32x4 __attribute__((ext_vector_type(4)));

#define A_TOTAL 262144
#define NMAP    131072

// ---------------- W1 slices f32 -> bf16 ------------------------------------
// slices: 0=map_W1a(qubit) 1=map_W1b(qpu) 2=sch_W1a(gate) 3=sch_W1b(time)
__global__ __launch_bounds__(256) void k_w1b16(
    const float* __restrict__ mW1, const float* __restrict__ sW1,
    bf16_t* __restrict__ dst) {
  int e = blockIdx.x * 256 + threadIdx.x;     // 0..262143
  int slice = e >> 16, idx = e & 65535;
  int n = idx >> 8, k = idx & 255;
  float v;
  switch (slice) {
    case 0:  v = mW1[n * 512 + k]; break;
    case 1:  v = mW1[n * 512 + 256 + k]; break;
    case 2:  v = sW1[n * 512 + k]; break;
    default: v = sW1[n * 512 + 256 + k]; break;
  }
  dst[e] = (bf16_t)v;
}

// ---------------- W2 -> extended weights [272][256] per table --------------
// rows 0..255 = W2 (bf16), rows 256..271 zeroed (qw rows filled by k_front)
__global__ __launch_bounds__(256) void k_w2ext(
    const float* __restrict__ mW2, const float* __restrict__ sW2,
    bf16_t* __restrict__ wext) {
  int row = blockIdx.x, tab = blockIdx.y, k = threadIdx.x;
  const float* W2 = tab ? sW2 : mW2;
  bf16_t v = (row < 256) ? (bf16_t)W2[row * 256 + k] : (bf16_t)0.f;
  wext[(size_t)tab * 272 * 256 + (size_t)row * 256 + k] = v;
}

// ---------------- column partial sums of all_embeddings [131072][256] ------
__global__ __launch_bounds__(256) void k_mean(const float* __restrict__ A,
                                              float* __restrict__ part) {
  int t = threadIdx.x, b = blockIdx.x;        // 256 blocks x 512 rows
  const float* base = A + (size_t)b * 512 * 256 + t;
  float s = 0.f;
  for (int r = 0; r < 512; ++r) s += base[(size_t)r * 256];
  part[b * 256 + t] = s;
}

// ---------------- g -> query MLP -> q -> qk -> qw rows of Wext -------------
__global__ __launch_bounds__(256) void k_front(
    const float* __restrict__ meanPart,
    const float* __restrict__ qgW1, const float* __restrict__ qgb1,
    const float* __restrict__ qgW2, const float* __restrict__ qgb2,
    const float* __restrict__ Wq,  const float* __restrict__ bq,
    const float* __restrict__ Wk,
    const float* __restrict__ mW2, const float* __restrict__ sW2,
    bf16_t* __restrict__ wext) {
  __shared__ float g[256], h1[256], qry[256], qv[256];
  __shared__ float qks[4][256];
  int t = threadIdx.x;
  float s = 0.f;
  for (int b = 0; b < 256; ++b) s += meanPart[b * 256 + t];
  g[t] = s * (1.0f / 131072.0f);
  __syncthreads();
  {
    const f32x4* row = (const f32x4*)(qgW1 + (size_t)t * 256);
    float acc = 0.f;
    for (int k = 0; k < 64; ++k) {
      f32x4 w = row[k];
      acc += w[0] * g[4 * k] + w[1] * g[4 * k + 1] + w[2] * g[4 * k + 2] + w[3] * g[4 * k + 3];
    }
    h1[t] = fmaxf(acc + qgb1[t], 0.f);
  }
  __syncthreads();
  {
    const f32x4* row = (const f32x4*)(qgW2 + (size_t)t * 256);
    float acc = 0.f;
    for (int k = 0; k < 64; ++k) {
      f32x4 w = row[k];
      acc += w[0] * h1[4 * k] + w[1] * h1[4 * k + 1] + w[2] * h1[4 * k + 2] + w[3] * h1[4 * k + 3];
    }
    qry[t] = acc + qgb2[t];
  }
  __syncthreads();
  {
    const f32x4* row = (const f32x4*)(Wq + (size_t)t * 256);
    float acc = 0.f;
    for (int k = 0; k < 64; ++k) {
      f32x4 w = row[k];
      acc += w[0] * qry[4 * k] + w[1] * qry[4 * k + 1] + w[2] * qry[4 * k + 2] + w[3] * qry[4 * k + 3];
    }
    qv[t] = acc + bq[t];
  }
  __syncthreads();
  // qk[h][n] = (1/8) sum_d qv[h*64+d] * Wk[h*64+d][n]
  for (int h = 0; h < 4; ++h) {
    float acc = 0.f;
    for (int d = 0; d < 64; ++d) acc += qv[h * 64 + d] * Wk[(size_t)(h * 64 + d) * 256 + t];
    qks[h][t] = acc * 0.125f;
  }
  __syncthreads();
  // qw[h][k] = sum_n qk[h][n] * W2[n][k]  -> Wext rows 256..259 (both tables)
  for (int tab = 0; tab < 2; ++tab) {
    const float* W2 = tab ? sW2 : mW2;
    float acc0 = 0.f, acc1 = 0.f, acc2 = 0.f, acc3 = 0.f;
    for (int n = 0; n < 256; ++n) {
      float wv = W2[(size_t)n * 256 + t];
      acc0 += qks[0][n] * wv;
      acc1 += qks[1][n] * wv;
      acc2 += qks[2][n] * wv;
      acc3 += qks[3][n] * wv;
    }
    bf16_t* dst = wext + (size_t)tab * 272 * 256;
    dst[(256 + 0) * 256 + t] = (bf16_t)acc0;
    dst[(256 + 1) * 256 + t] = (bf16_t)acc1;
    dst[(256 + 2) * 256 + t] = (bf16_t)acc2;
    dst[(256 + 3) * 256 + t] = (bf16_t)acc3;
  }
}

// ---------------- GEMM (direct): C[M][256] = bf16( A_f32 @ W^T + bias ) ----
// 512 thr = 8 waves (2 row x 4 col), tile 128x256, K=256.
__global__ __launch_bounds__(512) void gemm_direct2(
    const float* __restrict__ A, int M,
    const bf16_t* __restrict__ W, const float* __restrict__ bias,
    bf16_t* __restrict__ C) {
  int t = threadIdx.x;
  int w = t >> 6, lane = t & 63;
  int lm = lane & 15, q = lane >> 4;
  int m0 = blockIdx.x * 128 + (w & 1) * 64;
  int c0 = (w >> 1) * 64;
  int rows[4];
#pragma unroll
  for (int i = 0; i < 4; ++i) {
    int m = m0 + i * 16 + lm;
    rows[i] = m < M ? m : M - 1;
  }
  f32x4 acc[4][4] = {};
#pragma unroll
  for (int kt = 0; kt < 8; ++kt) {
    int k0 = kt * 32 + q * 8;
    bf16x8 b[4];
#pragma unroll
    for (int j = 0; j < 4; ++j)
      b[j] = *(const bf16x8*)(W + (size_t)(c0 + j * 16 + lm) * 256 + k0);
#pragma unroll
    for (int i = 0; i < 4; ++i) {
      const float* src = A + (size_t)rows[i] * 256 + k0;
      f32x4 lo = *(const f32x4*)src;
      f32x4 hi = *(const f32x4*)(src + 4);
      bf16x8 a;
#pragma unroll
      for (int x = 0; x < 4; ++x) { a[x] = (bf16_t)lo[x]; a[x + 4] = (bf16_t)hi[x]; }
#pragma unroll
      for (int j = 0; j < 4; ++j)
        acc[i][j] = __builtin_amdgcn_mfma_f32_16x16x32_bf16(a, b[j], acc[i][j], 0, 0, 0);
    }
  }
#pragma unroll
  for (int j = 0; j < 4; ++j) {
    int col = c0 + j * 16 + lm;
    float bb = bias ? bias[col] : 0.f;
#pragma unroll
    for (int i = 0; i < 4; ++i)
#pragma unroll
      for (int r = 0; r < 4; ++r) {
        int m = m0 + i * 16 + q * 4 + r;
        if (m < M) C[(size_t)m * 256 + col] = (bf16_t)(acc[i][j][r] + bb);
      }
  }
}

// ---------------- GEMM (gather, LDS-staged) + fused scores -----------------
// 256 thr = 4 waves (col split), tile 64 rows x 256 cols, K in 2 chunks of 128.
// X = relu(Pa[ia]+Pb[ib]) staged in LDS; scores from 4 extra Wext columns.
__global__ __launch_bounds__(256, 4) void gemm_gather2(
    const bf16_t* __restrict__ Pa, const bf16_t* __restrict__ Pb,
    const int* __restrict__ idxA, const int* __restrict__ idxB,
    const bf16_t* __restrict__ Wext, const float* __restrict__ bias,
    bf16_t* __restrict__ C,
    float* __restrict__ scores, int scoreBase,
    float* __restrict__ partMax, int pmBase) {
  __shared__ bf16_t X[64][136];      // 17408 B, +8 pad -> 2-way banks (free)
  __shared__ float sred[4];
  int t = threadIdx.x;
  int w = t >> 6, lane = t & 63;
  int lm = lane & 15, q = lane >> 4;
  int cw = w * 64;
  int r = t >> 2, qa = t & 3;        // 4 threads per row, 64B each from Pa,Pb
  int row0 = blockIdx.x * 64;
  int ia = idxA[row0 + r], ib = idxB[row0 + r];
  const bf16_t* paBase = Pa + (size_t)ia * 256 + qa * 32;
  const bf16_t* pbBase = Pb + (size_t)ib * 256 + qa * 32;

  f32x4 acc[4][4] = {};
  f32x4 accs[4] = {};
  bool doScore = (w == 0);

  for (int c = 0; c < 2; ++c) {
    if (c) __syncthreads();          // all reads of prev chunk done
    const bf16_t* pa = paBase + c * 128;
    const bf16_t* pb = pbBase + c * 128;
    bf16x8 va[4], vb[4];
#pragma unroll
    for (int i = 0; i < 4; ++i) { va[i] = *(const bf16x8*)(pa + i * 8); vb[i] = *(const bf16x8*)(pb + i * 8); }
#pragma unroll
    for (int i = 0; i < 4; ++i) {
      bf16x8 x;
#pragma unroll
      for (int e = 0; e < 8; ++e)
        x[e] = (bf16_t)fmaxf((float)va[i][e] + (float)vb[i][e], 0.f);
      *(bf16x8*)&X[r][qa * 32 + i * 8] = x;
    }
    __syncthreads();
#pragma unroll
    for (int kt = 0; kt < 4; ++kt) {
      int kl = kt * 32 + q * 8;
      int kg = c * 128 + kl;
      bf16x8 a[4];
#pragma unroll
      for (int i = 0; i < 4; ++i)
        a[i] = *(const bf16x8*)&X[i * 16 + lm][kl];
#pragma unroll
      for (int j = 0; j < 4; ++j) {
        bf16x8 b = *(const bf16x8*)(Wext + (size_t)(cw + j * 16 + lm) * 256 + kg);
#pragma unroll
        for (int i = 0; i < 4; ++i)
          acc[i][j] = __builtin_amdgcn_mfma_f32_16x16x32_bf16(a[i], b, acc[i][j], 0, 0, 0);
      }
      if (doScore) {
        bf16x8 bs = *(const bf16x8*)(Wext + (size_t)(256 + lm) * 256 + kg);
#pragma unroll
        for (int i = 0; i < 4; ++i)
          accs[i] = __builtin_amdgcn_mfma_f32_16x16x32_bf16(a[i], bs, accs[i], 0, 0, 0);
      }
    }
  }
  // keys epilogue
#pragma unroll
  for (int j = 0; j < 4; ++j) {
    int col = cw + j * 16 + lm;
    float bb = bias[col];
#pragma unroll
    for (int i = 0; i < 4; ++i)
#pragma unroll
      for (int rr = 0; rr < 4; ++rr) {
        int m = i * 16 + q * 4 + rr;
        C[(size_t)(row0 + m) * 256 + col] = (bf16_t)(acc[i][j][rr] + bb);
      }
  }
  // scores epilogue (wave 0; lanes lm<4 hold head lm)
  float hmax = -3.4e38f;
  if (doScore) {
    if (lm < 4) {
#pragma unroll
      for (int i = 0; i < 4; ++i)
#pragma unroll
        for (int rr = 0; rr < 4; ++rr) {
          int m = i * 16 + q * 4 + rr;
          float v = accs[i][rr];
          scores[(size_t)lm * A_TOTAL + scoreBase + row0 + m] = v;
          hmax = fmaxf(hmax, v);
        }
    }
    float m1 = fmaxf(hmax, __shfl_xor(hmax, 16));
    float m2 = fmaxf(m1, __shfl_xor(m1, 32));
    if (lane < 4) sred[lane] = m2;
  }
  __syncthreads();
  if (t < 4) partMax[t * 4096 + pmBase + blockIdx.x] = sred[t];
}

// ---------------- per-head max over 4096 block partials --------------------
__global__ __launch_bounds__(256) void k_smax2(const float* __restrict__ pM,
                                               float* __restrict__ Mh) {
  int t = threadIdx.x;
  __shared__ float red[256];
  for (int h = 0; h < 4; ++h) {
    float m = -3.4e38f;
    for (int i = t; i < 4096; i += 256) m = fmaxf(m, pM[h * 4096 + i]);
    red[t] = m;
    __syncthreads();
    for (int s = 128; s > 0; s >>= 1) {
      if (t < s) red[t] = fmaxf(red[t], red[t + s]);
      __syncthreads();
    }
    if (t == 0) Mh[h] = red[0];
    __syncthreads();
  }
}

__global__ __launch_bounds__(256) void k_ssum(const float* __restrict__ scores,
                                              const float* __restrict__ Mh,
                                              float* __restrict__ part) {
  int b = blockIdx.x, t = threadIdx.x;    // 256 blocks, head = b>>6
  float m = Mh[b >> 6];
  const float* base = scores + (size_t)b * 4096;
  float s = 0.f;
  for (int i = 0; i < 16; ++i) s += __expf(base[i * 256 + t] - m);
  __shared__ float red[256];
  red[t] = s;
  __syncthreads();
  for (int st = 128; st > 0; st >>= 1) {
    if (t < st) red[t] += red[t + st];
    __syncthreads();
  }
  if (t == 0) part[b] = red[0];
}

__global__ __launch_bounds__(256) void k_ssum2(const float* __restrict__ part,
                                               float* __restrict__ invS) {
  int t = threadIdx.x;
  __shared__ float red[256];
  red[t] = part[t];
  __syncthreads();
  for (int s = 32; s > 0; s >>= 1) {
    if ((t & 63) < s) red[t] += red[t + s];
    __syncthreads();
  }
  if ((t & 63) == 0) invS[t >> 6] = 1.0f / red[t];
}

// ---------------- u[h] = sum_a w[h,a] * keys[a] ----------------------------
__global__ __launch_bounds__(256) void k_u(
    const bf16_t* __restrict__ keys, const float* __restrict__ scores,
    const float* __restrict__ Mh, const float* __restrict__ invS,
    float* __restrict__ u) {
  __shared__ float wl[4][512];
  __shared__ float uloc[2][4][256];
  int t = threadIdx.x;
  int a0 = blockIdx.x * 512;            // 512 blocks x 512 rows
#pragma unroll
  for (int i = 0; i < 8; ++i) {
    int e = i * 256 + t;                // 0..2047
    int h = e >> 9, rr = e & 511;
    wl[h][rr] = __expf(scores[(size_t)h * A_TOTAL + a0 + rr] - Mh[h]) * invS[h];
  }
  __syncthreads();
  int tc = t & 127, rh = t >> 7;
  float acc[4][2] = {};
  for (int rr = 0; rr < 256; ++rr) {
    int a = a0 + rh * 256 + rr;
    bf16x2 kv = *(const bf16x2*)(keys + (size_t)a * 256 + tc * 2);
    float f0 = (float)kv[0], f1 = (float)kv[1];
#pragma unroll
    for (int h = 0; h < 4; ++h) {
      float wv = wl[h][rh * 256 + rr];
      acc[h][0] += wv * f0;
      acc[h][1] += wv * f1;
    }
  }
#pragma unroll
  for (int h = 0; h < 4; ++h) {
    uloc[rh][h][tc * 2]     = acc[h][0];
    uloc[rh][h][tc * 2 + 1] = acc[h][1];
  }
  __syncthreads();
#pragma unroll
  for (int h = 0; h < 4; ++h)
    atomicAdd(&u[h * 256 + t], uloc[0][h][t] + uloc[1][h][t]);
}

// ---------------- ctx = u @ Wv_h^T + bv ; attn_out = ctx @ Wo^T + bo -------
__global__ __launch_bounds__(256) void k_attn(
    const float* __restrict__ u, const float* __restrict__ Wv,
    const float* __restrict__ bv, const float* __restrict__ Wo,
    const float* __restrict__ bo, float* __restrict__ attn_out,
    bf16_t* __restrict__ attn_pad) {
  __shared__ float ctx[256];
  int t = threadIdx.x;
  int h = t >> 6;
  const float* uh = u + h * 256;
  {
    const f32x4* row = (const f32x4*)(Wv + (size_t)t * 256);
    float acc = 0.f;
    for (int k = 0; k < 64; ++k) {
      f32x4 w = row[k];
      acc += w[0] * uh[4 * k] + w[1] * uh[4 * k + 1] + w[2] * uh[4 * k + 2] + w[3] * uh[4 * k + 3];
    }
    ctx[t] = acc + bv[t];
  }
  __syncthreads();
  {
    const f32x4* row = (const f32x4*)(Wo + (size_t)t * 256);
    float acc = 0.f;
    for (int k = 0; k < 64; ++k) {
      f32x4 w = row[k];
      acc += w[0] * ctx[4 * k] + w[1] * ctx[4 * k + 1] + w[2] * ctx[4 * k + 2] + w[3] * ctx[4 * k + 3];
    }
    float v = acc + bo[t];
    attn_out[t] = v;
    attn_pad[t] = (bf16_t)v;
#pragma unroll
    for (int i = 1; i < 16; ++i) attn_pad[i * 256 + t] = (bf16_t)0.f;
  }
}

// ---------------- logits[a] = keys[a] . attn_out (MFMA) + block max --------
__global__ __launch_bounds__(256) void k_logits2(
    const bf16_t* __restrict__ keys, const bf16_t* __restrict__ attn_pad,
    float* __restrict__ out_logits, float* __restrict__ blockMax) {
  int t = threadIdx.x;
  int w = t >> 6, lane = t & 63;
  int lm = lane & 15, q = lane >> 4;
  int m0 = blockIdx.x * 256 + w * 64;
  bf16x8 b[8];
#pragma unroll
  for (int kt = 0; kt < 8; ++kt)
    b[kt] = *(const bf16x8*)(attn_pad + lm * 256 + kt * 32 + q * 8);
  f32x4 acc[4] = {};
#pragma unroll
  for (int i = 0; i < 4; ++i) {
    const bf16_t* arow = keys + (size_t)(m0 + i * 16 + lm) * 256 + q * 8;
#pragma unroll
    for (int kt = 0; kt < 8; ++kt) {
      bf16x8 a = *(const bf16x8*)(arow + kt * 32);
      acc[i] = __builtin_amdgcn_mfma_f32_16x16x32_bf16(a, b[kt], acc[i], 0, 0, 0);
    }
  }
  float lmax = -3.4e38f;
  if (lm == 0) {
#pragma unroll
    for (int i = 0; i < 4; ++i)
#pragma unroll
      for (int rr = 0; rr < 4; ++rr) {
        float v = acc[i][rr];
        out_logits[m0 + i * 16 + q * 4 + rr] = v;
        lmax = fmaxf(lmax, v);
      }
  }
  float m1 = fmaxf(lmax, __shfl_xor(lmax, 16));
  float m2 = fmaxf(m1, __shfl_xor(m1, 32));
  __shared__ float red[4];
  if (lane == 0) red[w] = m2;
  __syncthreads();
  if (t == 0)
    blockMax[blockIdx.x] = fmaxf(fmaxf(red[0], red[1]), fmaxf(red[2], red[3]));
}

__global__ __launch_bounds__(256) void k_lred1(const float* __restrict__ bm,
                                               float* __restrict__ Ml) {
  int t = threadIdx.x;
  float m = -3.4e38f;
  for (int i = t; i < 1024; i += 256) m = fmaxf(m, bm[i]);
  __shared__ float red[256];
  red[t] = m;
  __syncthreads();
  for (int s = 128; s > 0; s >>= 1) {
    if (t < s) red[t] = fmaxf(red[t], red[t + s]);
    __syncthreads();
  }
  if (t == 0) Ml[0] = red[0];
}

__global__ __launch_bounds__(256) void k_lsum(const float* __restrict__ logits,
                                              const float* __restrict__ Ml,
                                              float* __restrict__ part) {
  int t = threadIdx.x, b = blockIdx.x;   // 512 blocks x 512 elems
  float m = Ml[0];
  float s = __expf(logits[b * 512 + t] - m) + __expf(logits[b * 512 + 256 + t] - m);
  __shared__ float red[256];
  red[t] = s;
  __syncthreads();
  for (int st = 128; st > 0; st >>= 1) {
    if (t < st) red[t] += red[t + st];
    __syncthreads();
  }
  if (t == 0) part[b] = red[0];
}

__global__ __launch_bounds__(256) void k_lred2(const float* __restrict__ part,
                                               float* __restrict__ invSl) {
  int t = threadIdx.x;
  float s = part[t] + part[t + 256];
  __shared__ float red[256];
  red[t] = s;
  __syncthreads();
  for (int st = 128; st > 0; st >>= 1) {
    if (t < st) red[t] += red[t + st];
    __syncthreads();
  }
  if (t == 0) invSl[0] = 1.0f / red[0];
}

__global__ __launch_bounds__(256) void k_probs(const float* __restrict__ logits,
                                               const float* __restrict__ Ml,
                                               const float* __restrict__ invSl,
                                               float* __restrict__ probs) {
  int i = blockIdx.x * 256 + threadIdx.x;
  probs[i] = __expf(logits[i] - Ml[0]) * invSl[0];
}

// ===========================================================================
extern "C" void kernel_launch(void* const* d_in, const int* in_sizes, int n_in,
                              void* d_out, int out_size, void* d_ws, size_t ws_size,
                              hipStream_t stream) {
  const float* qubit_emb = (const float*)d_in[0];
  const float* qpu_emb   = (const float*)d_in[1];
  const float* gate_emb  = (const float*)d_in[2];
  const float* all_emb   = (const float*)d_in[3];
  const float* time_tab  = (const float*)d_in[4];
  const float* map_W1 = (const float*)d_in[5];
  const float* map_b1 = (const float*)d_in[6];
  const float* map_W2 = (const float*)d_in[7];
  const float* map_b2 = (const float*)d_in[8];
  const float* sch_W1 = (const float*)d_in[9];
  const float* sch_b1 = (const float*)d_in[10];
  const float* sch_W2 = (const float*)d_in[11];
  const float* sch_b2 = (const float*)d_in[12];
  const float* qg_W1 = (const float*)d_in[13];
  const float* qg_b1 = (const float*)d_in[14];
  const float* qg_W2 = (const float*)d_in[15];
  const float* qg_b2 = (const float*)d_in[16];
  const float* Wq = (const float*)d_in[17];
  const float* bq = (const float*)d_in[18];
  const float* Wk = (const float*)d_in[19];
  // d_in[20] = attn_bk: per-head constant, softmax-invariant -> unused
  const float* Wv = (const float*)d_in[21];
  const float* bv = (const float*)d_in[22];
  const float* Wo = (const float*)d_in[23];
  const float* bo = (const float*)d_in[24];
  const int* map_qubit  = (const int*)d_in[25];
  const int* map_qpu    = (const int*)d_in[26];
  const int* sched_gate = (const int*)d_in[27];
  const int* sched_time = (const int*)d_in[28];
  (void)in_sizes; (void)n_in; (void)out_size;

  char* ws = (char*)d_ws;
  size_t off = 0;
  auto alloc = [&](size_t b) { size_t r = off; off += (b + 255) & ~(size_t)255; return r; };
  size_t KEYS  = alloc((size_t)A_TOTAL * 256 * 2);   // bf16 keys
  size_t PQ    = alloc((size_t)65536 * 256 * 2);     // bf16 qubit proj
  size_t PG    = alloc((size_t)65536 * 256 * 2);     // bf16 gate proj
  size_t PP    = alloc((size_t)64 * 256 * 2);        // bf16 qpu proj (+b1)
  size_t PT    = alloc((size_t)1024 * 256 * 2);      // bf16 time proj (+b1)
  size_t W1B   = alloc((size_t)4 * 65536 * 2);       // bf16 W1 slices
  size_t WEXT  = alloc((size_t)2 * 272 * 256 * 2);   // bf16 extended W2 (+qw)
  size_t SCORE = alloc((size_t)4 * A_TOTAL * 4);     // f32 scores [4][A]
  size_t MPART = alloc((size_t)256 * 256 * 4);       // mean partials
  size_t APAD  = alloc((size_t)16 * 256 * 2);        // bf16 attn_out padded
  size_t ATTN  = alloc(256 * 4);
  size_t U     = alloc(4 * 256 * 4);
  size_t PMAX  = alloc(4 * 4096 * 4);
  size_t MH    = alloc(4 * 4);
  size_t SINV  = alloc(4 * 4);
  size_t BMAX  = alloc(1024 * 4);
  size_t ML    = alloc(4);
  size_t SLINV = alloc(4);
  size_t LPART = alloc(512 * 4);
  size_t SPART = alloc(256 * 4);
  if (off > ws_size) return;  // insufficient scratch -> loud validation fail

  bf16_t* keysP  = (bf16_t*)(ws + KEYS);
  bf16_t* pqP    = (bf16_t*)(ws + PQ);
  bf16_t* pgP    = (bf16_t*)(ws + PG);
  bf16_t* ppP    = (bf16_t*)(ws + PP);
  bf16_t* ptP    = (bf16_t*)(ws + PT);
  bf16_t* w1bP   = (bf16_t*)(ws + W1B);
  bf16_t* wextP  = (bf16_t*)(ws + WEXT);
  float*  scoreP = (float*)(ws + SCORE);
  float*  mpartP = (float*)(ws + MPART);
  bf16_t* apadP  = (bf16_t*)(ws + APAD);
  float*  attnP  = (float*)(ws + ATTN);
  float*  uP     = (float*)(ws + U);
  float*  pmaxP  = (float*)(ws + PMAX);
  float*  mhP    = (float*)(ws + MH);
  float*  sinvP  = (float*)(ws + SINV);
  float*  bmaxP  = (float*)(ws + BMAX);
  float*  mlP    = (float*)(ws + ML);
  float*  slinvP = (float*)(ws + SLINV);
  float*  lpartP = (float*)(ws + LPART);
  float*  spartP = (float*)(ws + SPART);

  float* probsOut  = (float*)d_out;
  float* logitsOut = probsOut + A_TOTAL;

  hipMemsetAsync(uP, 0, 4 * 256 * 4, stream);

  k_w1b16<<<1024, 256, 0, stream>>>(map_W1, sch_W1, w1bP);
  k_w2ext<<<dim3(272, 2), 256, 0, stream>>>(map_W2, sch_W2, wextP);
  k_mean<<<256, 256, 0, stream>>>(all_emb, mpartP);
  k_front<<<1, 256, 0, stream>>>(mpartP, qg_W1, qg_b1, qg_W2, qg_b2,
                                 Wq, bq, Wk, map_W2, sch_W2, wextP);

  // table projections (layer-1 halves)
  gemm_direct2<<<512, 512, 0, stream>>>(qubit_emb, 65536, w1bP + 0 * 65536, nullptr, pqP);
  gemm_direct2<<<512, 512, 0, stream>>>(gate_emb, 65536, w1bP + 2 * 65536, nullptr, pgP);
  gemm_direct2<<<1,   512, 0, stream>>>(qpu_emb, 64,    w1bP + 1 * 65536, map_b1, ppP);
  gemm_direct2<<<8,   512, 0, stream>>>(time_tab, 1000, w1bP + 3 * 65536, sch_b1, ptP);

  // keys + fused scores
  gemm_gather2<<<2048, 256, 0, stream>>>(pqP, ppP, map_qubit, map_qpu,
                                         wextP, map_b2, keysP,
                                         scoreP, 0, pmaxP, 0);
  gemm_gather2<<<2048, 256, 0, stream>>>(pgP, ptP, sched_gate, sched_time,
                                         wextP + 272 * 256, sch_b2,
                                         keysP + (size_t)NMAP * 256,
                                         scoreP, NMAP, pmaxP, 2048);

  // softmax stats over scores
  k_smax2<<<1, 256, 0, stream>>>(pmaxP, mhP);
  k_ssum<<<256, 256, 0, stream>>>(scoreP, mhP, spartP);
  k_ssum2<<<1, 256, 0, stream>>>(spartP, sinvP);

  // weighted key sum -> ctx -> attn_out
  k_u<<<512, 256, 0, stream>>>(keysP, scoreP, mhP, sinvP, uP);
  k_attn<<<1, 256, 0, stream>>>(uP, Wv, bv, Wo, bo, attnP, apadP);

  // logits + global softmax
  k_logits2<<<1024, 256, 0, stream>>>(keysP, apadP, logitsOut, bmaxP);
  k_lred1<<<1, 256, 0, stream>>>(bmaxP, mlP);
  k_lsum<<<512, 256, 0, stream>>>(logitsOut, mlP, lpartP);
  k_lred2<<<1, 256, 0, stream>>>(lpartP, slinvP);
  k_probs<<<1024, 256, 0, stream>>>(logitsOut, mlP, slinvP, probsOut);
}